// Round 1
// baseline (3762.381 us; speedup 1.0000x reference)
//
#include <hip/hip_runtime.h>
#include <hip/hip_bf16.h>

#define N_NODES 100000
#define N_EDGES 1600000
#define IN_DIM_ 256
#define HID_ 256
#define OUT_ 64
#define KSTEPS 10

typedef __attribute__((ext_vector_type(4))) float f32x4;
typedef __attribute__((ext_vector_type(8))) __bf16 bf16x8;
typedef __attribute__((ext_vector_type(8))) unsigned short u16x8;

static __device__ __forceinline__ unsigned short f2bf(float f) {
    union { float f; unsigned int u; } v; v.f = f;
    unsigned int u = v.u;
    unsigned int r = u + 0x7FFFu + ((u >> 16) & 1u);  // RNE
    return (unsigned short)(r >> 16);
}

// ---------------- small setup kernels ----------------

__global__ void gamma_kernel(const float* __restrict__ alpha, float* __restrict__ gamma) {
    if (threadIdx.x == 0) {
        float m = alpha[0];
        for (int i = 1; i <= KSTEPS; ++i) m = fmaxf(m, alpha[i]);
        float e[KSTEPS + 1];
        float s = 0.f;
        for (int i = 0; i <= KSTEPS; ++i) { e[i] = expf(alpha[i] - m); s += e[i]; }
        float inv = 1.f / s;
        for (int i = 0; i <= KSTEPS; ++i) gamma[i] = e[i] * inv;
    }
}

__global__ void deg_kernel(const int* __restrict__ row, float* __restrict__ deg, int E) {
    int e = blockIdx.x * 256 + threadIdx.x;
    if (e < E) atomicAdd(&deg[row[e]], 1.0f);
}

__global__ void dis_kernel(const float* __restrict__ deg, float* __restrict__ dis, int n) {
    int i = blockIdx.x * 256 + threadIdx.x;
    if (i < n) {
        float d = deg[i];
        dis[i] = d > 0.f ? rsqrtf(d) : 0.f;  // deg>=1 when >0, so max(d,1)=d
    }
}

__global__ void norm_kernel(const int* __restrict__ row, const int* __restrict__ col,
                            const float* __restrict__ dis, float* __restrict__ nrm, int E) {
    int e = blockIdx.x * 256 + threadIdx.x;
    if (e < E) nrm[e] = dis[row[e]] * dis[col[e]];
}

// ---------------- MLP: bf16 MFMA GEMMs ----------------
// GEMM1: h1 = relu(x @ W1 + b1), x f32 [M,256], W1 f32 [256,256] -> h1 bf16 [M,256]
// 64x64 tile, 4 waves (2x2), each wave 32x32 (2x2 frags of 16x16x32)

__global__ __launch_bounds__(256) void gemm1_kernel(const float* __restrict__ x,
                                                    const float* __restrict__ W1,
                                                    const float* __restrict__ b1,
                                                    unsigned short* __restrict__ h1, int M) {
    __shared__ unsigned short As[64][40];  // [m][k], pad 40 (80B stride, 16B aligned)
    __shared__ unsigned short Bs[64][40];  // [n][k] transposed

    const int tid = threadIdx.x;
    const int lane = tid & 63;
    const int w = tid >> 6;
    const int wr = w >> 1, wc = w & 1;
    const int row0 = blockIdx.x * 64;
    const int n0 = blockIdx.y * 64;

    const int am = tid >> 2;           // 0..63
    const int ak = (tid & 3) * 8;      // 0,8,16,24
    const int bk = tid >> 3;           // 0..31
    const int bn = (tid & 7) * 8;      // 0..56

    f32x4 acc[2][2] = {};

    for (int kk = 0; kk < 256; kk += 32) {
        // stage A (f32 -> bf16)
        {
            int gr = row0 + am;
            u16x8 av;
            if (gr < M) {
                const float* p = x + (size_t)gr * IN_DIM_ + kk + ak;
                #pragma unroll
                for (int j = 0; j < 8; ++j) av[j] = f2bf(p[j]);
            } else {
                #pragma unroll
                for (int j = 0; j < 8; ++j) av[j] = 0;
            }
            *(u16x8*)&As[am][ak] = av;
        }
        // stage B transposed
        {
            const float* p = W1 + (size_t)(kk + bk) * HID_ + n0 + bn;
            #pragma unroll
            for (int j = 0; j < 8; ++j) Bs[bn + j][bk] = f2bf(p[j]);
        }
        __syncthreads();

        const int fr = lane & 15;
        const int ko = (lane >> 4) * 8;
        bf16x8 a[2], b[2];
        #pragma unroll
        for (int mi = 0; mi < 2; ++mi) a[mi] = *(const bf16x8*)&As[wr * 32 + mi * 16 + fr][ko];
        #pragma unroll
        for (int ni = 0; ni < 2; ++ni) b[ni] = *(const bf16x8*)&Bs[wc * 32 + ni * 16 + fr][ko];
        #pragma unroll
        for (int mi = 0; mi < 2; ++mi)
            #pragma unroll
            for (int ni = 0; ni < 2; ++ni)
                acc[mi][ni] = __builtin_amdgcn_mfma_f32_16x16x32_bf16(a[mi], b[ni], acc[mi][ni], 0, 0, 0);
        __syncthreads();
    }

    // epilogue: bias + relu -> bf16
    const int fr = lane & 15;
    const int rg = (lane >> 4) * 4;
    #pragma unroll
    for (int mi = 0; mi < 2; ++mi) {
        #pragma unroll
        for (int r = 0; r < 4; ++r) {
            int gm = row0 + wr * 32 + mi * 16 + rg + r;
            if (gm < M) {
                #pragma unroll
                for (int ni = 0; ni < 2; ++ni) {
                    int gn = n0 + wc * 32 + ni * 16 + fr;
                    float v = acc[mi][ni][r] + b1[gn];
                    v = fmaxf(v, 0.f);
                    h1[(size_t)gm * HID_ + gn] = f2bf(v);
                }
            }
        }
    }
}

// GEMM2: h = h1 @ W2 + b2 (h1 bf16 [M,256], W2 f32 [256,64]) -> h f32 [M,64]
// also writes out = gamma[0]*h (acc init)
__global__ __launch_bounds__(256) void gemm2_kernel(const unsigned short* __restrict__ h1,
                                                    const float* __restrict__ W2,
                                                    const float* __restrict__ b2,
                                                    const float* __restrict__ gamma,
                                                    float* __restrict__ h,
                                                    float* __restrict__ out, int M) {
    __shared__ unsigned short As[64][40];
    __shared__ unsigned short Bs[64][40];

    const int tid = threadIdx.x;
    const int lane = tid & 63;
    const int w = tid >> 6;
    const int wr = w >> 1, wc = w & 1;
    const int row0 = blockIdx.x * 64;

    const int am = tid >> 2;
    const int ak = (tid & 3) * 8;
    const int bk = tid >> 3;
    const int bn = (tid & 7) * 8;

    f32x4 acc[2][2] = {};

    for (int kk = 0; kk < 256; kk += 32) {
        {
            int gr = row0 + am;
            if (gr < M) {
                *(u16x8*)&As[am][ak] = *(const u16x8*)&h1[(size_t)gr * HID_ + kk + ak];
            } else {
                u16x8 z = {};
                *(u16x8*)&As[am][ak] = z;
            }
        }
        {
            const float* p = W2 + (size_t)(kk + bk) * OUT_ + bn;
            #pragma unroll
            for (int j = 0; j < 8; ++j) Bs[bn + j][bk] = f2bf(p[j]);
        }
        __syncthreads();

        const int fr = lane & 15;
        const int ko = (lane >> 4) * 8;
        bf16x8 a[2], b[2];
        #pragma unroll
        for (int mi = 0; mi < 2; ++mi) a[mi] = *(const bf16x8*)&As[wr * 32 + mi * 16 + fr][ko];
        #pragma unroll
        for (int ni = 0; ni < 2; ++ni) b[ni] = *(const bf16x8*)&Bs[wc * 32 + ni * 16 + fr][ko];
        #pragma unroll
        for (int mi = 0; mi < 2; ++mi)
            #pragma unroll
            for (int ni = 0; ni < 2; ++ni)
                acc[mi][ni] = __builtin_amdgcn_mfma_f32_16x16x32_bf16(a[mi], b[ni], acc[mi][ni], 0, 0, 0);
        __syncthreads();
    }

    const float g0 = gamma[0];
    const int fr = lane & 15;
    const int rg = (lane >> 4) * 4;
    #pragma unroll
    for (int mi = 0; mi < 2; ++mi) {
        #pragma unroll
        for (int r = 0; r < 4; ++r) {
            int gm = row0 + wr * 32 + mi * 16 + rg + r;
            if (gm < M) {
                #pragma unroll
                for (int ni = 0; ni < 2; ++ni) {
                    int gn = wc * 32 + ni * 16 + fr;
                    float v = acc[mi][ni][r] + b2[gn];
                    h[(size_t)gm * OUT_ + gn] = v;
                    out[(size_t)gm * OUT_ + gn] = g0 * v;
                }
            }
        }
    }
}

// ---------------- propagation ----------------
// one wave per edge, lane = feature; coalesced 256B gather + coalesced atomics
__global__ __launch_bounds__(256) void scatter_kernel(const int* __restrict__ row,
                                                      const int* __restrict__ col,
                                                      const float* __restrict__ nrm,
                                                      const float* __restrict__ hc,
                                                      float* __restrict__ hn, int E) {
    int e = blockIdx.x * 4 + (threadIdx.x >> 6);
    if (e >= E) return;
    int f = threadIdx.x & 63;
    int r = row[e], c = col[e];
    float v = hc[(size_t)c * OUT_ + f] * nrm[e];
    atomicAdd(&hn[(size_t)r * OUT_ + f], v);
}

// out += gamma[k]*hn ; zero old h_cur (becomes next h_new)
__global__ __launch_bounds__(256) void axpy_zero_kernel(float* __restrict__ out,
                                                        const float* __restrict__ hn,
                                                        float* __restrict__ hc_old,
                                                        const float* __restrict__ gamma,
                                                        int k, int n4) {
    int i = blockIdx.x * 256 + threadIdx.x;
    if (i < n4) {
        float g = gamma[k];
        f32x4 v = ((const f32x4*)hn)[i];
        f32x4 o = ((f32x4*)out)[i];
        ((f32x4*)out)[i] = o + g * v;
        f32x4 z = {};
        ((f32x4*)hc_old)[i] = z;
    }
}

// ---------------- launcher ----------------
// ws layout (floats):
//   nrm   : E                          (6.4 MB)
//   h_a   : N*64                       (25.6 MB)
//   gamma : 16
//   X     : max(h1 bf16 N*256 = 12.8M floats, h_b N*64 + deg N + dis N)
// total ~83.2 MB. h1 (dead after gemm2) aliases h_b/deg/dis.
extern "C" void kernel_launch(void* const* d_in, const int* in_sizes, int n_in,
                              void* d_out, int out_size, void* d_ws, size_t ws_size,
                              hipStream_t stream) {
    const float* x = (const float*)d_in[0];
    const int* ei = (const int*)d_in[1];
    const float* W1 = (const float*)d_in[2];
    const float* b1 = (const float*)d_in[3];
    const float* W2 = (const float*)d_in[4];
    const float* b2 = (const float*)d_in[5];
    const float* alpha = (const float*)d_in[6];
    const int* row = ei;
    const int* col = ei + N_EDGES;

    float* ws = (float*)d_ws;
    float* nrm = ws;
    float* h_a = nrm + N_EDGES;
    float* gamma = h_a + (size_t)N_NODES * OUT_;
    float* X = gamma + 16;
    unsigned short* h1 = (unsigned short*)X;          // N*256 bf16
    float* h_b = X;                                   // N*64 (aliases h1, ok)
    float* deg = X + (size_t)N_NODES * OUT_;          // N   (aliases h1, ok)
    float* dis = deg + N_NODES;                       // N   (aliases h1, ok)
    float* out = (float*)d_out;

    hipMemsetAsync(deg, 0, N_NODES * sizeof(float), stream);
    gamma_kernel<<<1, 64, 0, stream>>>(alpha, gamma);
    deg_kernel<<<(N_EDGES + 255) / 256, 256, 0, stream>>>(row, deg, N_EDGES);
    dis_kernel<<<(N_NODES + 255) / 256, 256, 0, stream>>>(deg, dis, N_NODES);
    norm_kernel<<<(N_EDGES + 255) / 256, 256, 0, stream>>>(row, col, dis, nrm, N_EDGES);

    gemm1_kernel<<<dim3((N_NODES + 63) / 64, HID_ / 64), 256, 0, stream>>>(x, W1, b1, h1, N_NODES);
    gemm2_kernel<<<dim3((N_NODES + 63) / 64, 1), 256, 0, stream>>>(h1, W2, b2, gamma, h_a, out, N_NODES);

    hipMemsetAsync(h_b, 0, (size_t)N_NODES * OUT_ * sizeof(float), stream);

    float* hc = h_a;
    float* hn = h_b;
    for (int k = 1; k <= KSTEPS; ++k) {
        scatter_kernel<<<(N_EDGES + 3) / 4, 256, 0, stream>>>(row, col, nrm, hc, hn, N_EDGES);
        axpy_zero_kernel<<<((N_NODES * OUT_ / 4) + 255) / 256, 256, 0, stream>>>(
            out, hn, hc, gamma, k, N_NODES * OUT_ / 4);
        float* t = hc; hc = hn; hn = t;
    }
}

// Round 3
// 1157.038 us; speedup vs baseline: 3.2517x; 3.2517x over previous
//
#include <hip/hip_runtime.h>
#include <hip/hip_bf16.h>

#define N_NODES 100000
#define N_EDGES 1600000
#define IN_DIM_ 256
#define HID_ 256
#define OUT_ 64
#define KSTEPS 10

typedef __attribute__((ext_vector_type(4))) float f32x4;
typedef __attribute__((ext_vector_type(8))) __bf16 bf16x8;
typedef __attribute__((ext_vector_type(8))) unsigned short u16x8;

static __device__ __forceinline__ unsigned short f2bf(float f) {
    union { float f; unsigned int u; } v; v.f = f;
    unsigned int u = v.u;
    unsigned int r = u + 0x7FFFu + ((u >> 16) & 1u);  // RNE
    return (unsigned short)(r >> 16);
}

// ---------------- small setup kernels ----------------

__global__ void gamma_kernel(const float* __restrict__ alpha, float* __restrict__ gamma) {
    if (threadIdx.x == 0) {
        float m = alpha[0];
        for (int i = 1; i <= KSTEPS; ++i) m = fmaxf(m, alpha[i]);
        float e[KSTEPS + 1];
        float s = 0.f;
        for (int i = 0; i <= KSTEPS; ++i) { e[i] = expf(alpha[i] - m); s += e[i]; }
        float inv = 1.f / s;
        for (int i = 0; i <= KSTEPS; ++i) gamma[i] = e[i] * inv;
    }
}

__global__ void deg_kernel(const int* __restrict__ row, int* __restrict__ deg, int E) {
    int e = blockIdx.x * 256 + threadIdx.x;
    if (e < E) atomicAdd(&deg[row[e]], 1);
}

__global__ void dis_kernel(const int* __restrict__ deg, float* __restrict__ dis, int n) {
    int i = blockIdx.x * 256 + threadIdx.x;
    if (i < n) {
        int d = deg[i];
        dis[i] = d > 0 ? rsqrtf((float)d) : 0.f;
    }
}

// single-block exclusive scan over deg -> off[0..n], off[n]=E
#define SCAN_T 1024
__global__ __launch_bounds__(SCAN_T) void scan_kernel(const int* __restrict__ deg,
                                                      int* __restrict__ off, int n) {
    __shared__ int sums[SCAN_T];
    int t = threadIdx.x;
    int per = (n + SCAN_T - 1) / SCAN_T;
    int s0 = t * per;
    int s1 = min(s0 + per, n);
    int local = 0;
    for (int i = s0; i < s1; ++i) local += deg[i];
    sums[t] = local;
    __syncthreads();
    for (int s = 1; s < SCAN_T; s <<= 1) {
        int a = (t >= s) ? sums[t - s] : 0;
        __syncthreads();
        sums[t] += a;
        __syncthreads();
    }
    int excl = sums[t] - local;
    for (int i = s0; i < s1; ++i) {
        off[i] = excl;
        excl += deg[i];
    }
    if (t == SCAN_T - 1) off[n] = sums[t];
}

// counting-sort edges into CSR: ecsr[off[r]+pos] = {col, dis[r]*dis[col]}
__global__ void csr_scatter_kernel(const int* __restrict__ row, const int* __restrict__ col,
                                   const float* __restrict__ dis, const int* __restrict__ off,
                                   int* __restrict__ cursor, int2* __restrict__ ecsr, int E) {
    int e = blockIdx.x * 256 + threadIdx.x;
    if (e < E) {
        int r = row[e], c = col[e];
        float w = dis[r] * dis[c];
        int pos = atomicAdd(&cursor[r], 1);
        int2 p;
        p.x = c;
        p.y = __float_as_int(w);
        ecsr[(size_t)off[r] + pos] = p;
    }
}

// ---------------- MLP: bf16 MFMA GEMMs ----------------

__global__ __launch_bounds__(256) void gemm1_kernel(const float* __restrict__ x,
                                                    const float* __restrict__ W1,
                                                    const float* __restrict__ b1,
                                                    unsigned short* __restrict__ h1, int M) {
    __shared__ unsigned short As[64][40];
    __shared__ unsigned short Bs[64][40];

    const int tid = threadIdx.x;
    const int lane = tid & 63;
    const int w = tid >> 6;
    const int wr = w >> 1, wc = w & 1;
    const int row0 = blockIdx.x * 64;
    const int n0 = blockIdx.y * 64;

    const int am = tid >> 2;
    const int ak = (tid & 3) * 8;
    const int bk = tid >> 3;
    const int bn = (tid & 7) * 8;

    f32x4 acc[2][2] = {};

    for (int kk = 0; kk < 256; kk += 32) {
        {
            int gr = row0 + am;
            u16x8 av;
            if (gr < M) {
                const float* p = x + (size_t)gr * IN_DIM_ + kk + ak;
                #pragma unroll
                for (int j = 0; j < 8; ++j) av[j] = f2bf(p[j]);
            } else {
                #pragma unroll
                for (int j = 0; j < 8; ++j) av[j] = 0;
            }
            *(u16x8*)&As[am][ak] = av;
        }
        {
            const float* p = W1 + (size_t)(kk + bk) * HID_ + n0 + bn;
            #pragma unroll
            for (int j = 0; j < 8; ++j) Bs[bn + j][bk] = f2bf(p[j]);
        }
        __syncthreads();

        const int fr = lane & 15;
        const int ko = (lane >> 4) * 8;
        bf16x8 a[2], b[2];
        #pragma unroll
        for (int mi = 0; mi < 2; ++mi) a[mi] = *(const bf16x8*)&As[wr * 32 + mi * 16 + fr][ko];
        #pragma unroll
        for (int ni = 0; ni < 2; ++ni) b[ni] = *(const bf16x8*)&Bs[wc * 32 + ni * 16 + fr][ko];
        #pragma unroll
        for (int mi = 0; mi < 2; ++mi)
            #pragma unroll
            for (int ni = 0; ni < 2; ++ni)
                acc[mi][ni] = __builtin_amdgcn_mfma_f32_16x16x32_bf16(a[mi], b[ni], acc[mi][ni], 0, 0, 0);
        __syncthreads();
    }

    const int fr = lane & 15;
    const int rg = (lane >> 4) * 4;
    #pragma unroll
    for (int mi = 0; mi < 2; ++mi) {
        #pragma unroll
        for (int r = 0; r < 4; ++r) {
            int gm = row0 + wr * 32 + mi * 16 + rg + r;
            if (gm < M) {
                #pragma unroll
                for (int ni = 0; ni < 2; ++ni) {
                    int gn = n0 + wc * 32 + ni * 16 + fr;
                    float v = acc[mi][ni][r] + b1[gn];
                    v = fmaxf(v, 0.f);
                    h1[(size_t)gm * HID_ + gn] = f2bf(v);
                }
            }
        }
    }
}

__global__ __launch_bounds__(256) void gemm2_kernel(const unsigned short* __restrict__ h1,
                                                    const float* __restrict__ W2,
                                                    const float* __restrict__ b2,
                                                    const float* __restrict__ gamma,
                                                    float* __restrict__ h,
                                                    float* __restrict__ out, int M) {
    __shared__ unsigned short As[64][40];
    __shared__ unsigned short Bs[64][40];

    const int tid = threadIdx.x;
    const int lane = tid & 63;
    const int w = tid >> 6;
    const int wr = w >> 1, wc = w & 1;
    const int row0 = blockIdx.x * 64;

    const int am = tid >> 2;
    const int ak = (tid & 3) * 8;
    const int bk = tid >> 3;
    const int bn = (tid & 7) * 8;

    f32x4 acc[2][2] = {};

    for (int kk = 0; kk < 256; kk += 32) {
        {
            int gr = row0 + am;
            if (gr < M) {
                *(u16x8*)&As[am][ak] = *(const u16x8*)&h1[(size_t)gr * HID_ + kk + ak];
            } else {
                u16x8 z = {};
                *(u16x8*)&As[am][ak] = z;
            }
        }
        {
            const float* p = W2 + (size_t)(kk + bk) * OUT_ + bn;
            #pragma unroll
            for (int j = 0; j < 8; ++j) Bs[bn + j][bk] = f2bf(p[j]);
        }
        __syncthreads();

        const int fr = lane & 15;
        const int ko = (lane >> 4) * 8;
        bf16x8 a[2], b[2];
        #pragma unroll
        for (int mi = 0; mi < 2; ++mi) a[mi] = *(const bf16x8*)&As[wr * 32 + mi * 16 + fr][ko];
        #pragma unroll
        for (int ni = 0; ni < 2; ++ni) b[ni] = *(const bf16x8*)&Bs[wc * 32 + ni * 16 + fr][ko];
        #pragma unroll
        for (int mi = 0; mi < 2; ++mi)
            #pragma unroll
            for (int ni = 0; ni < 2; ++ni)
                acc[mi][ni] = __builtin_amdgcn_mfma_f32_16x16x32_bf16(a[mi], b[ni], acc[mi][ni], 0, 0, 0);
        __syncthreads();
    }

    const float g0 = gamma[0];
    const int fr = lane & 15;
    const int rg = (lane >> 4) * 4;
    #pragma unroll
    for (int mi = 0; mi < 2; ++mi) {
        #pragma unroll
        for (int r = 0; r < 4; ++r) {
            int gm = row0 + wr * 32 + mi * 16 + rg + r;
            if (gm < M) {
                #pragma unroll
                for (int ni = 0; ni < 2; ++ni) {
                    int gn = wc * 32 + ni * 16 + fr;
                    float v = acc[mi][ni][r] + b2[gn];
                    h[(size_t)gm * OUT_ + gn] = v;
                    out[(size_t)gm * OUT_ + gn] = g0 * v;
                }
            }
        }
    }
}

// ---------------- propagation: CSR pull, no atomics ----------------
// one wave per node, lane = feature; fused out += gamma[k]*h_new
__global__ __launch_bounds__(256) void pull_kernel(const int* __restrict__ off,
                                                   const int2* __restrict__ ecsr,
                                                   const float* __restrict__ hc,
                                                   float* __restrict__ hn,
                                                   float* __restrict__ out,
                                                   const float* __restrict__ gamma,
                                                   int k, int n) {
    int node = blockIdx.x * 4 + (threadIdx.x >> 6);
    if (node >= n) return;
    int f = threadIdx.x & 63;
    int s = off[node], e = off[node + 1];
    float g = gamma[k];
    float acc = 0.f;
    int j = s;
    for (; j + 4 <= e; j += 4) {
        int2 p0 = ecsr[j], p1 = ecsr[j + 1], p2 = ecsr[j + 2], p3 = ecsr[j + 3];
        float v0 = hc[(size_t)p0.x * OUT_ + f];
        float v1 = hc[(size_t)p1.x * OUT_ + f];
        float v2 = hc[(size_t)p2.x * OUT_ + f];
        float v3 = hc[(size_t)p3.x * OUT_ + f];
        acc += __int_as_float(p0.y) * v0;
        acc += __int_as_float(p1.y) * v1;
        acc += __int_as_float(p2.y) * v2;
        acc += __int_as_float(p3.y) * v3;
    }
    for (; j < e; ++j) {
        int2 p = ecsr[j];
        acc += __int_as_float(p.y) * hc[(size_t)p.x * OUT_ + f];
    }
    size_t o = (size_t)node * OUT_ + f;
    hn[o] = acc;
    out[o] += g * acc;
}

// ---------------- launcher ----------------
extern "C" void kernel_launch(void* const* d_in, const int* in_sizes, int n_in,
                              void* d_out, int out_size, void* d_ws, size_t ws_size,
                              hipStream_t stream) {
    const float* x = (const float*)d_in[0];
    const int* ei = (const int*)d_in[1];
    const float* W1 = (const float*)d_in[2];
    const float* b1 = (const float*)d_in[3];
    const float* W2 = (const float*)d_in[4];
    const float* b2 = (const float*)d_in[5];
    const float* alpha = (const float*)d_in[6];
    const int* row = ei;
    const int* col = ei + N_EDGES;
    float* out = (float*)d_out;

    // ws layout (256B-aligned regions)
    char* wsb = (char*)d_ws;
    size_t p = 0;
    auto alloc = [&](size_t bytes) { size_t r = p; p += (bytes + 255) & ~255ull; return r; };
    float* gamma = (float*)(wsb + alloc(16 * 4));
    int* off     = (int*)(wsb + alloc((N_NODES + 1) * 4));
    int* cursor  = (int*)(wsb + alloc(N_NODES * 4));
    int* deg     = (int*)(wsb + alloc(N_NODES * 4));
    float* dis   = (float*)(wsb + alloc(N_NODES * 4));
    int2* ecsr   = (int2*)(wsb + alloc((size_t)N_EDGES * 8));
    float* h_a   = (float*)(wsb + alloc((size_t)N_NODES * OUT_ * 4));
    float* h_b   = (float*)(wsb + alloc((size_t)N_NODES * OUT_ * 4));
    unsigned short* h1 = (unsigned short*)h_b;  // N*256 bf16 = 12.8MB, dead before h_b first written

    // R2 bugfix: separate exact-size memsets (single combined memset left the
    // padded tail of deg poisoned -> garbage off[] -> OOB ecsr writes -> crash)
    hipMemsetAsync(cursor, 0, N_NODES * sizeof(int), stream);
    hipMemsetAsync(deg, 0, N_NODES * sizeof(int), stream);
    gamma_kernel<<<1, 64, 0, stream>>>(alpha, gamma);
    deg_kernel<<<(N_EDGES + 255) / 256, 256, 0, stream>>>(row, deg, N_EDGES);
    dis_kernel<<<(N_NODES + 255) / 256, 256, 0, stream>>>(deg, dis, N_NODES);
    scan_kernel<<<1, SCAN_T, 0, stream>>>(deg, off, N_NODES);
    csr_scatter_kernel<<<(N_EDGES + 255) / 256, 256, 0, stream>>>(row, col, dis, off, cursor,
                                                                  ecsr, N_EDGES);

    gemm1_kernel<<<dim3((N_NODES + 63) / 64, HID_ / 64), 256, 0, stream>>>(x, W1, b1, h1, N_NODES);
    gemm2_kernel<<<dim3((N_NODES + 63) / 64, 1), 256, 0, stream>>>(h1, W2, b2, gamma, h_a, out,
                                                                   N_NODES);

    float* hc = h_a;
    float* hn = h_b;
    for (int k = 1; k <= KSTEPS; ++k) {
        pull_kernel<<<(N_NODES + 3) / 4, 256, 0, stream>>>(off, ecsr, hc, hn, out, gamma, k,
                                                           N_NODES);
        float* t = hc; hc = hn; hn = t;
    }
}

// Round 4
// 893.320 us; speedup vs baseline: 4.2117x; 1.2952x over previous
//
#include <hip/hip_runtime.h>
#include <hip/hip_bf16.h>

#define N_NODES 100000
#define N_EDGES 1600000
#define IN_DIM_ 256
#define HID_ 256
#define OUT_ 64
#define KSTEPS 10

typedef __attribute__((ext_vector_type(4))) float f32x4;
typedef __attribute__((ext_vector_type(8))) __bf16 bf16x8;
typedef __attribute__((ext_vector_type(8))) unsigned short u16x8;

static __device__ __forceinline__ unsigned short f2bf(float f) {
    union { float f; unsigned int u; } v; v.f = f;
    unsigned int u = v.u;
    unsigned int r = u + 0x7FFFu + ((u >> 16) & 1u);  // RNE
    return (unsigned short)(r >> 16);
}
static __device__ __forceinline__ float bflo(unsigned int v) {
    return __uint_as_float(v << 16);
}
static __device__ __forceinline__ float bfhi(unsigned int v) {
    return __uint_as_float(v & 0xFFFF0000u);
}

// ---------------- small setup kernels ----------------

__global__ void gamma_kernel(const float* __restrict__ alpha, float* __restrict__ gamma) {
    if (threadIdx.x == 0) {
        float m = alpha[0];
        for (int i = 1; i <= KSTEPS; ++i) m = fmaxf(m, alpha[i]);
        float e[KSTEPS + 1];
        float s = 0.f;
        for (int i = 0; i <= KSTEPS; ++i) { e[i] = expf(alpha[i] - m); s += e[i]; }
        float inv = 1.f / s;
        for (int i = 0; i <= KSTEPS; ++i) gamma[i] = e[i] * inv;
    }
}

__global__ void deg_kernel(const int* __restrict__ row, int* __restrict__ deg, int E) {
    int e = blockIdx.x * 256 + threadIdx.x;
    if (e < E) atomicAdd(&deg[row[e]], 1);
}

__global__ void dis_kernel(const int* __restrict__ deg, float* __restrict__ dis, int n) {
    int i = blockIdx.x * 256 + threadIdx.x;
    if (i < n) {
        int d = deg[i];
        dis[i] = d > 0 ? rsqrtf((float)d) : 0.f;
    }
}

// ---------------- hierarchical scan (3 kernels, ~6us) ----------------
// R3 lesson: single-block scan = 1 CU = 160us. Parallelize.

__global__ __launch_bounds__(256) void scan_sum_kernel(const int* __restrict__ deg,
                                                       int* __restrict__ bsum, int n) {
    __shared__ int s[256];
    int t = threadIdx.x;
    int i = blockIdx.x * 256 + t;
    s[t] = (i < n) ? deg[i] : 0;
    __syncthreads();
    for (int st = 128; st > 0; st >>= 1) {
        if (t < st) s[t] += s[t + st];
        __syncthreads();
    }
    if (t == 0) bsum[blockIdx.x] = s[0];
}

__global__ __launch_bounds__(512) void scan_block_kernel(int* __restrict__ bsum,
                                                         int* __restrict__ off,
                                                         int nblk, int n) {
    __shared__ int s[512];
    int t = threadIdx.x;
    int v = (t < nblk) ? bsum[t] : 0;
    s[t] = v;
    __syncthreads();
    for (int st = 1; st < 512; st <<= 1) {
        int a = (t >= st) ? s[t - st] : 0;
        __syncthreads();
        s[t] += a;
        __syncthreads();
    }
    if (t < nblk) bsum[t] = s[t] - v;  // exclusive
    if (t == 511) off[n] = s[511];     // total = E
}

__global__ __launch_bounds__(256) void scan_final_kernel(const int* __restrict__ deg,
                                                         const int* __restrict__ bsum,
                                                         int* __restrict__ off, int n) {
    __shared__ int s[256];
    int t = threadIdx.x;
    int i = blockIdx.x * 256 + t;
    int v = (i < n) ? deg[i] : 0;
    s[t] = v;
    __syncthreads();
    for (int st = 1; st < 256; st <<= 1) {
        int a = (t >= st) ? s[t - st] : 0;
        __syncthreads();
        s[t] += a;
        __syncthreads();
    }
    if (i < n) off[i] = bsum[blockIdx.x] + s[t] - v;
}

// counting-sort edges into CSR: ecsr[off[r]+pos] = {col, dis[r]*dis[col]}
__global__ void csr_scatter_kernel(const int* __restrict__ row, const int* __restrict__ col,
                                   const float* __restrict__ dis, const int* __restrict__ off,
                                   int* __restrict__ cursor, int2* __restrict__ ecsr, int E) {
    int e = blockIdx.x * 256 + threadIdx.x;
    if (e < E) {
        int r = row[e], c = col[e];
        float w = dis[r] * dis[c];
        int pos = atomicAdd(&cursor[r], 1);
        int2 p;
        p.x = c;
        p.y = __float_as_int(w);
        ecsr[(size_t)off[r] + pos] = p;
    }
}

// ---------------- MLP: bf16 MFMA GEMMs ----------------

__global__ __launch_bounds__(256) void gemm1_kernel(const float* __restrict__ x,
                                                    const float* __restrict__ W1,
                                                    const float* __restrict__ b1,
                                                    unsigned short* __restrict__ h1, int M) {
    __shared__ unsigned short As[64][40];
    __shared__ unsigned short Bs[64][40];

    const int tid = threadIdx.x;
    const int lane = tid & 63;
    const int w = tid >> 6;
    const int wr = w >> 1, wc = w & 1;
    const int row0 = blockIdx.x * 64;
    const int n0 = blockIdx.y * 64;

    const int am = tid >> 2;
    const int ak = (tid & 3) * 8;
    const int bk = tid >> 3;
    const int bn = (tid & 7) * 8;

    f32x4 acc[2][2] = {};

    for (int kk = 0; kk < 256; kk += 32) {
        {
            int gr = row0 + am;
            u16x8 av;
            if (gr < M) {
                const float* p = x + (size_t)gr * IN_DIM_ + kk + ak;
                #pragma unroll
                for (int j = 0; j < 8; ++j) av[j] = f2bf(p[j]);
            } else {
                #pragma unroll
                for (int j = 0; j < 8; ++j) av[j] = 0;
            }
            *(u16x8*)&As[am][ak] = av;
        }
        {
            const float* p = W1 + (size_t)(kk + bk) * HID_ + n0 + bn;
            #pragma unroll
            for (int j = 0; j < 8; ++j) Bs[bn + j][bk] = f2bf(p[j]);
        }
        __syncthreads();

        const int fr = lane & 15;
        const int ko = (lane >> 4) * 8;
        bf16x8 a[2], b[2];
        #pragma unroll
        for (int mi = 0; mi < 2; ++mi) a[mi] = *(const bf16x8*)&As[wr * 32 + mi * 16 + fr][ko];
        #pragma unroll
        for (int ni = 0; ni < 2; ++ni) b[ni] = *(const bf16x8*)&Bs[wc * 32 + ni * 16 + fr][ko];
        #pragma unroll
        for (int mi = 0; mi < 2; ++mi)
            #pragma unroll
            for (int ni = 0; ni < 2; ++ni)
                acc[mi][ni] = __builtin_amdgcn_mfma_f32_16x16x32_bf16(a[mi], b[ni], acc[mi][ni], 0, 0, 0);
        __syncthreads();
    }

    const int fr = lane & 15;
    const int rg = (lane >> 4) * 4;
    #pragma unroll
    for (int mi = 0; mi < 2; ++mi) {
        #pragma unroll
        for (int r = 0; r < 4; ++r) {
            int gm = row0 + wr * 32 + mi * 16 + rg + r;
            if (gm < M) {
                #pragma unroll
                for (int ni = 0; ni < 2; ++ni) {
                    int gn = n0 + wc * 32 + ni * 16 + fr;
                    float v = acc[mi][ni][r] + b1[gn];
                    v = fmaxf(v, 0.f);
                    h1[(size_t)gm * HID_ + gn] = f2bf(v);
                }
            }
        }
    }
}

// GEMM2: h = h1 @ W2 + b2 -> h bf16 [M,64]; out = gamma0 * h (f32, pre-rounding)
__global__ __launch_bounds__(256) void gemm2_kernel(const unsigned short* __restrict__ h1,
                                                    const float* __restrict__ W2,
                                                    const float* __restrict__ b2,
                                                    const float* __restrict__ gamma,
                                                    unsigned short* __restrict__ h,
                                                    float* __restrict__ out, int M) {
    __shared__ unsigned short As[64][40];
    __shared__ unsigned short Bs[64][40];

    const int tid = threadIdx.x;
    const int lane = tid & 63;
    const int w = tid >> 6;
    const int wr = w >> 1, wc = w & 1;
    const int row0 = blockIdx.x * 64;

    const int am = tid >> 2;
    const int ak = (tid & 3) * 8;
    const int bk = tid >> 3;
    const int bn = (tid & 7) * 8;

    f32x4 acc[2][2] = {};

    for (int kk = 0; kk < 256; kk += 32) {
        {
            int gr = row0 + am;
            if (gr < M) {
                *(u16x8*)&As[am][ak] = *(const u16x8*)&h1[(size_t)gr * HID_ + kk + ak];
            } else {
                u16x8 z = {};
                *(u16x8*)&As[am][ak] = z;
            }
        }
        {
            const float* p = W2 + (size_t)(kk + bk) * OUT_ + bn;
            #pragma unroll
            for (int j = 0; j < 8; ++j) Bs[bn + j][bk] = f2bf(p[j]);
        }
        __syncthreads();

        const int fr = lane & 15;
        const int ko = (lane >> 4) * 8;
        bf16x8 a[2], b[2];
        #pragma unroll
        for (int mi = 0; mi < 2; ++mi) a[mi] = *(const bf16x8*)&As[wr * 32 + mi * 16 + fr][ko];
        #pragma unroll
        for (int ni = 0; ni < 2; ++ni) b[ni] = *(const bf16x8*)&Bs[wc * 32 + ni * 16 + fr][ko];
        #pragma unroll
        for (int mi = 0; mi < 2; ++mi)
            #pragma unroll
            for (int ni = 0; ni < 2; ++ni)
                acc[mi][ni] = __builtin_amdgcn_mfma_f32_16x16x32_bf16(a[mi], b[ni], acc[mi][ni], 0, 0, 0);
        __syncthreads();
    }

    const float g0 = gamma[0];
    const int fr = lane & 15;
    const int rg = (lane >> 4) * 4;
    #pragma unroll
    for (int mi = 0; mi < 2; ++mi) {
        #pragma unroll
        for (int r = 0; r < 4; ++r) {
            int gm = row0 + wr * 32 + mi * 16 + rg + r;
            if (gm < M) {
                #pragma unroll
                for (int ni = 0; ni < 2; ++ni) {
                    int gn = wc * 32 + ni * 16 + fr;
                    float v = acc[mi][ni][r] + b2[gn];
                    h[(size_t)gm * OUT_ + gn] = f2bf(v);
                    out[(size_t)gm * OUT_ + gn] = g0 * v;
                }
            }
        }
    }
}

// ---------------- propagation: CSR pull, bf16 state, 2 edges/wave ----------------
// half-wave per edge parity: lanes 0..31 even edges, 32..63 odd edges,
// each lane covers 2 features via ushort2; combine halves with shfl_xor(32).
__global__ __launch_bounds__(256) void pull_kernel(const int* __restrict__ off,
                                                   const int2* __restrict__ ecsr,
                                                   const unsigned short* __restrict__ hc,
                                                   unsigned short* __restrict__ hn,
                                                   float* __restrict__ out,
                                                   const float* __restrict__ gamma,
                                                   int k, int n) {
    int node = blockIdx.x * 4 + (threadIdx.x >> 6);
    if (node >= n) return;
    int lane = threadIdx.x & 63;
    int half = lane >> 5;
    int fl = (lane & 31) * 2;
    int s = off[node], e = off[node + 1];
    float acc0 = 0.f, acc1 = 0.f;

    int j = s + half;
    for (; j + 2 < e; j += 4) {
        int2 pa = ecsr[j];
        int2 pb = ecsr[j + 2];
        unsigned int va = *(const unsigned int*)&hc[(size_t)pa.x * OUT_ + fl];
        unsigned int vb = *(const unsigned int*)&hc[(size_t)pb.x * OUT_ + fl];
        float wa = __int_as_float(pa.y);
        float wb = __int_as_float(pb.y);
        acc0 += wa * bflo(va);
        acc1 += wa * bfhi(va);
        acc0 += wb * bflo(vb);
        acc1 += wb * bfhi(vb);
    }
    if (j < e) {
        int2 p = ecsr[j];
        unsigned int v = *(const unsigned int*)&hc[(size_t)p.x * OUT_ + fl];
        float w = __int_as_float(p.y);
        acc0 += w * bflo(v);
        acc1 += w * bfhi(v);
    }

    acc0 += __shfl_xor(acc0, 32);
    acc1 += __shfl_xor(acc1, 32);

    if (lane < 32) {
        float g = gamma[k];
        size_t o = (size_t)node * OUT_ + fl;
        unsigned int packed = (unsigned int)f2bf(acc0) | ((unsigned int)f2bf(acc1) << 16);
        *(unsigned int*)&hn[o] = packed;
        float2* op = (float2*)&out[o];
        float2 ov = *op;
        ov.x += g * acc0;
        ov.y += g * acc1;
        *op = ov;
    }
}

// ---------------- launcher ----------------
extern "C" void kernel_launch(void* const* d_in, const int* in_sizes, int n_in,
                              void* d_out, int out_size, void* d_ws, size_t ws_size,
                              hipStream_t stream) {
    const float* x = (const float*)d_in[0];
    const int* ei = (const int*)d_in[1];
    const float* W1 = (const float*)d_in[2];
    const float* b1 = (const float*)d_in[3];
    const float* W2 = (const float*)d_in[4];
    const float* b2 = (const float*)d_in[5];
    const float* alpha = (const float*)d_in[6];
    const int* row = ei;
    const int* col = ei + N_EDGES;
    float* out = (float*)d_out;

    const int NBLK = (N_NODES + 255) / 256;  // 391

    // ws layout (256B-aligned regions), total ~78.5 MB
    char* wsb = (char*)d_ws;
    size_t p = 0;
    auto alloc = [&](size_t bytes) { size_t r = p; p += (bytes + 255) & ~255ull; return r; };
    float* gamma = (float*)(wsb + alloc(16 * 4));
    int* off     = (int*)(wsb + alloc((N_NODES + 1) * 4));
    int* cursor  = (int*)(wsb + alloc(N_NODES * 4));
    int* deg     = (int*)(wsb + alloc(N_NODES * 4));
    float* dis   = (float*)(wsb + alloc(N_NODES * 4));
    int* bsum    = (int*)(wsb + alloc(512 * 4));
    int2* ecsr   = (int2*)(wsb + alloc((size_t)N_EDGES * 8));
    unsigned short* h1  = (unsigned short*)(wsb + alloc((size_t)N_NODES * HID_ * 2));  // 51.2MB
    unsigned short* h_a = (unsigned short*)(wsb + alloc((size_t)N_NODES * OUT_ * 2));  // 12.8MB
    unsigned short* h_b = h1;  // h1 dead after gemm2; h_b first written in pull step 1

    hipMemsetAsync(cursor, 0, N_NODES * sizeof(int), stream);
    hipMemsetAsync(deg, 0, N_NODES * sizeof(int), stream);
    gamma_kernel<<<1, 64, 0, stream>>>(alpha, gamma);
    deg_kernel<<<(N_EDGES + 255) / 256, 256, 0, stream>>>(row, deg, N_EDGES);
    dis_kernel<<<NBLK, 256, 0, stream>>>(deg, dis, N_NODES);
    scan_sum_kernel<<<NBLK, 256, 0, stream>>>(deg, bsum, N_NODES);
    scan_block_kernel<<<1, 512, 0, stream>>>(bsum, off, NBLK, N_NODES);
    scan_final_kernel<<<NBLK, 256, 0, stream>>>(deg, bsum, off, N_NODES);
    csr_scatter_kernel<<<(N_EDGES + 255) / 256, 256, 0, stream>>>(row, col, dis, off, cursor,
                                                                  ecsr, N_EDGES);

    gemm1_kernel<<<dim3((N_NODES + 63) / 64, HID_ / 64), 256, 0, stream>>>(x, W1, b1, h1, N_NODES);
    gemm2_kernel<<<dim3((N_NODES + 63) / 64, 1), 256, 0, stream>>>(h1, W2, b2, gamma, h_a, out,
                                                                   N_NODES);

    unsigned short* hc = h_a;
    unsigned short* hn = h_b;
    for (int k = 1; k <= KSTEPS; ++k) {
        pull_kernel<<<(N_NODES + 3) / 4, 256, 0, stream>>>(off, ecsr, hc, hn, out, gamma, k,
                                                           N_NODES);
        unsigned short* t = hc; hc = hn; hn = t;
    }
}

// Round 6
// 789.998 us; speedup vs baseline: 4.7625x; 1.1308x over previous
//
#include <hip/hip_runtime.h>
#include <hip/hip_bf16.h>

#define N_NODES 100000
#define N_EDGES 1600000
#define IN_DIM_ 256
#define HID_ 256
#define OUT_ 64
#define KSTEPS 10

typedef __attribute__((ext_vector_type(4))) float f32x4;
typedef __attribute__((ext_vector_type(8))) __bf16 bf16x8;
typedef __attribute__((ext_vector_type(8))) unsigned short u16x8;

static __device__ __forceinline__ unsigned short f2bf(float f) {
    union { float f; unsigned int u; } v; v.f = f;
    unsigned int u = v.u;
    unsigned int r = u + 0x7FFFu + ((u >> 16) & 1u);  // RNE
    return (unsigned short)(r >> 16);
}
static __device__ __forceinline__ float bflo(unsigned int v) {
    return __uint_as_float(v << 16);
}
static __device__ __forceinline__ float bfhi(unsigned int v) {
    return __uint_as_float(v & 0xFFFF0000u);
}

// ---------------- small setup kernels ----------------

__global__ void gamma_kernel(const float* __restrict__ alpha, float* __restrict__ gamma) {
    if (threadIdx.x == 0) {
        float m = alpha[0];
        for (int i = 1; i <= KSTEPS; ++i) m = fmaxf(m, alpha[i]);
        float e[KSTEPS + 1];
        float s = 0.f;
        for (int i = 0; i <= KSTEPS; ++i) { e[i] = expf(alpha[i] - m); s += e[i]; }
        float inv = 1.f / s;
        for (int i = 0; i <= KSTEPS; ++i) gamma[i] = e[i] * inv;
    }
}

__global__ void deg_kernel(const int* __restrict__ row, int* __restrict__ deg, int E) {
    int e = blockIdx.x * 256 + threadIdx.x;
    if (e < E) atomicAdd(&deg[row[e]], 1);
}

__global__ void dis_kernel(const int* __restrict__ deg, float* __restrict__ dis, int n) {
    int i = blockIdx.x * 256 + threadIdx.x;
    if (i < n) {
        int d = deg[i];
        dis[i] = d > 0 ? rsqrtf((float)d) : 0.f;
    }
}

// transpose+cast weights once: wT[n][k] = bf16(W[k][n])
__global__ void wcast_kernel(const float* __restrict__ W, unsigned short* __restrict__ wT,
                             int K, int N) {
    int k = blockIdx.x * 256 + threadIdx.x;
    int n = blockIdx.y;
    if (k < K) wT[(size_t)n * K + k] = f2bf(W[(size_t)k * N + n]);
}

// ---------------- hierarchical scan ----------------

__global__ __launch_bounds__(256) void scan_sum_kernel(const int* __restrict__ deg,
                                                       int* __restrict__ bsum, int n) {
    __shared__ int s[256];
    int t = threadIdx.x;
    int i = blockIdx.x * 256 + t;
    s[t] = (i < n) ? deg[i] : 0;
    __syncthreads();
    for (int st = 128; st > 0; st >>= 1) {
        if (t < st) s[t] += s[t + st];
        __syncthreads();
    }
    if (t == 0) bsum[blockIdx.x] = s[0];
}

__global__ __launch_bounds__(512) void scan_block_kernel(int* __restrict__ bsum,
                                                         int* __restrict__ off,
                                                         int nblk, int n) {
    __shared__ int s[512];
    int t = threadIdx.x;
    int v = (t < nblk) ? bsum[t] : 0;
    s[t] = v;
    __syncthreads();
    for (int st = 1; st < 512; st <<= 1) {
        int a = (t >= st) ? s[t - st] : 0;
        __syncthreads();
        s[t] += a;
        __syncthreads();
    }
    if (t < nblk) bsum[t] = s[t] - v;  // exclusive
    if (t == 511) off[n] = s[511];     // total = E
}

__global__ __launch_bounds__(256) void scan_final_kernel(const int* __restrict__ deg,
                                                         const int* __restrict__ bsum,
                                                         int* __restrict__ off, int n) {
    __shared__ int s[256];
    int t = threadIdx.x;
    int i = blockIdx.x * 256 + t;
    int v = (i < n) ? deg[i] : 0;
    s[t] = v;
    __syncthreads();
    for (int st = 1; st < 256; st <<= 1) {
        int a = (t >= st) ? s[t - st] : 0;
        __syncthreads();
        s[t] += a;
        __syncthreads();
    }
    if (i < n) off[i] = bsum[blockIdx.x] + s[t] - v;
}

__global__ void csr_scatter_kernel(const int* __restrict__ row, const int* __restrict__ col,
                                   const float* __restrict__ dis, const int* __restrict__ off,
                                   int* __restrict__ cursor, int2* __restrict__ ecsr, int E) {
    int e = blockIdx.x * 256 + threadIdx.x;
    if (e < E) {
        int r = row[e], c = col[e];
        float w = dis[r] * dis[c];
        int pos = atomicAdd(&cursor[r], 1);
        int2 p;
        p.x = c;
        p.y = __float_as_int(w);
        ecsr[(size_t)off[r] + pos] = p;
    }
}

// ---------------- MLP ----------------
// GEMM1 single-pass: block computes 64 rows x 256 cols. x fetched exactly once.
// 4 waves as 2x2; wave tile 32x128 = 2x8 frags of 16x16.
__global__ __launch_bounds__(256) void gemm1_kernel(const float* __restrict__ x,
                                                    const unsigned short* __restrict__ w1T,
                                                    const float* __restrict__ b1,
                                                    unsigned short* __restrict__ h1, int M) {
    __shared__ unsigned short As[64][40];
    __shared__ unsigned short Bs[256][40];

    const int tid = threadIdx.x;
    const int lane = tid & 63;
    const int w = tid >> 6;
    const int wr = w >> 1, wc = w & 1;          // wave tile: rows wr*32, cols wc*128
    const int row0 = blockIdx.x * 64;

    const int am = tid >> 2;
    const int ak = (tid & 3) * 8;

    f32x4 acc[2][8] = {};

    for (int kk = 0; kk < 256; kk += 32) {
        {
            int gr = row0 + am;
            u16x8 av;
            if (gr < M) {
                const float* p = x + (size_t)gr * IN_DIM_ + kk + ak;
                #pragma unroll
                for (int j = 0; j < 8; ++j) av[j] = f2bf(p[j]);
            } else {
                #pragma unroll
                for (int j = 0; j < 8; ++j) av[j] = 0;
            }
            *(u16x8*)&As[am][ak] = av;
        }
        {
            // thread t stages n-row t: 32 k-shorts = 4 x u16x8 (R5 bug: u16x8 is
            // 8 shorts, not 16 -- missing 8..15/24..31 left NaN garbage in LDS)
            const unsigned short* p = w1T + (size_t)tid * 256 + kk;
            *(u16x8*)&Bs[tid][0]  = *(const u16x8*)&p[0];
            *(u16x8*)&Bs[tid][8]  = *(const u16x8*)&p[8];
            *(u16x8*)&Bs[tid][16] = *(const u16x8*)&p[16];
            *(u16x8*)&Bs[tid][24] = *(const u16x8*)&p[24];
        }
        __syncthreads();

        const int fr = lane & 15;
        const int ko = (lane >> 4) * 8;
        bf16x8 a[2];
        #pragma unroll
        for (int mi = 0; mi < 2; ++mi) a[mi] = *(const bf16x8*)&As[wr * 32 + mi * 16 + fr][ko];
        #pragma unroll
        for (int ni = 0; ni < 8; ++ni) {
            bf16x8 b = *(const bf16x8*)&Bs[wc * 128 + ni * 16 + fr][ko];
            #pragma unroll
            for (int mi = 0; mi < 2; ++mi)
                acc[mi][ni] = __builtin_amdgcn_mfma_f32_16x16x32_bf16(a[mi], b, acc[mi][ni], 0, 0, 0);
        }
        __syncthreads();
    }

    const int fr = lane & 15;
    const int rg = (lane >> 4) * 4;
    #pragma unroll
    for (int mi = 0; mi < 2; ++mi) {
        #pragma unroll
        for (int r = 0; r < 4; ++r) {
            int gm = row0 + wr * 32 + mi * 16 + rg + r;
            if (gm < M) {
                #pragma unroll
                for (int ni = 0; ni < 8; ++ni) {
                    int gn = wc * 128 + ni * 16 + fr;
                    float v = acc[mi][ni][r] + b1[gn];
                    v = fmaxf(v, 0.f);
                    h1[(size_t)gm * HID_ + gn] = f2bf(v);
                }
            }
        }
    }
}

// GEMM2: h = h1 @ W2 + b2 -> h bf16 [M,64]; out = gamma0*h (f32 pre-rounding)
__global__ __launch_bounds__(256) void gemm2_kernel(const unsigned short* __restrict__ h1,
                                                    const unsigned short* __restrict__ w2T,
                                                    const float* __restrict__ b2,
                                                    const float* __restrict__ gamma,
                                                    unsigned short* __restrict__ h,
                                                    float* __restrict__ out, int M) {
    __shared__ unsigned short As[64][40];
    __shared__ unsigned short Bs[64][40];

    const int tid = threadIdx.x;
    const int lane = tid & 63;
    const int w = tid >> 6;
    const int wr = w >> 1, wc = w & 1;
    const int row0 = blockIdx.x * 64;

    const int am = tid >> 2;
    const int ak = (tid & 3) * 8;

    f32x4 acc[2][2] = {};

    for (int kk = 0; kk < 256; kk += 32) {
        {
            int gr = row0 + am;
            if (gr < M) {
                *(u16x8*)&As[am][ak] = *(const u16x8*)&h1[(size_t)gr * HID_ + kk + ak];
            } else {
                u16x8 z = {};
                *(u16x8*)&As[am][ak] = z;
            }
        }
        if (tid < 128) {
            // thread t (0..127): n = t>>1, half = t&1 -> 16 k-shorts = 2 x u16x8
            int n = tid >> 1, hf = (tid & 1) * 16;
            const unsigned short* p = &w2T[(size_t)n * 256 + kk + hf];
            *(u16x8*)&Bs[n][hf]     = *(const u16x8*)&p[0];
            *(u16x8*)&Bs[n][hf + 8] = *(const u16x8*)&p[8];
        }
        __syncthreads();

        const int fr = lane & 15;
        const int ko = (lane >> 4) * 8;
        bf16x8 a[2], b[2];
        #pragma unroll
        for (int mi = 0; mi < 2; ++mi) a[mi] = *(const bf16x8*)&As[wr * 32 + mi * 16 + fr][ko];
        #pragma unroll
        for (int ni = 0; ni < 2; ++ni) b[ni] = *(const bf16x8*)&Bs[wc * 32 + ni * 16 + fr][ko];
        #pragma unroll
        for (int mi = 0; mi < 2; ++mi)
            #pragma unroll
            for (int ni = 0; ni < 2; ++ni)
                acc[mi][ni] = __builtin_amdgcn_mfma_f32_16x16x32_bf16(a[mi], b[ni], acc[mi][ni], 0, 0, 0);
        __syncthreads();
    }

    const float g0 = gamma[0];
    const int fr = lane & 15;
    const int rg = (lane >> 4) * 4;
    #pragma unroll
    for (int mi = 0; mi < 2; ++mi) {
        #pragma unroll
        for (int r = 0; r < 4; ++r) {
            int gm = row0 + wr * 32 + mi * 16 + rg + r;
            if (gm < M) {
                #pragma unroll
                for (int ni = 0; ni < 2; ++ni) {
                    int gn = wc * 32 + ni * 16 + fr;
                    float v = acc[mi][ni][r] + b2[gn];
                    h[(size_t)gm * OUT_ + gn] = f2bf(v);
                    out[(size_t)gm * OUT_ + gn] = g0 * v;
                }
            }
        }
    }
}

// ---------------- propagation: CSR pull, bf16, unrolled x4 per half ----------------
__global__ __launch_bounds__(256) void pull_kernel(const int* __restrict__ off,
                                                   const int2* __restrict__ ecsr,
                                                   const unsigned short* __restrict__ hc,
                                                   unsigned short* __restrict__ hn,
                                                   float* __restrict__ out,
                                                   const float* __restrict__ gamma,
                                                   int k, int n) {
    int node = blockIdx.x * 4 + (threadIdx.x >> 6);
    if (node >= n) return;
    int lane = threadIdx.x & 63;
    int half = lane >> 5;
    int fl = (lane & 31) * 2;
    int s = off[node], e = off[node + 1];
    float acc0 = 0.f, acc1 = 0.f;

    int j = s + half;
    // 4 edges per half per iteration -> 4 outstanding gathers per lane
    for (; j + 6 < e; j += 8) {
        int2 pa = ecsr[j];
        int2 pb = ecsr[j + 2];
        int2 pc = ecsr[j + 4];
        int2 pd = ecsr[j + 6];
        unsigned int va = *(const unsigned int*)&hc[(size_t)pa.x * OUT_ + fl];
        unsigned int vb = *(const unsigned int*)&hc[(size_t)pb.x * OUT_ + fl];
        unsigned int vc = *(const unsigned int*)&hc[(size_t)pc.x * OUT_ + fl];
        unsigned int vd = *(const unsigned int*)&hc[(size_t)pd.x * OUT_ + fl];
        float wa = __int_as_float(pa.y), wb = __int_as_float(pb.y);
        float wc = __int_as_float(pc.y), wd = __int_as_float(pd.y);
        acc0 += wa * bflo(va); acc1 += wa * bfhi(va);
        acc0 += wb * bflo(vb); acc1 += wb * bfhi(vb);
        acc0 += wc * bflo(vc); acc1 += wc * bfhi(vc);
        acc0 += wd * bflo(vd); acc1 += wd * bfhi(vd);
    }
    for (; j + 2 < e; j += 4) {
        int2 pa = ecsr[j];
        int2 pb = ecsr[j + 2];
        unsigned int va = *(const unsigned int*)&hc[(size_t)pa.x * OUT_ + fl];
        unsigned int vb = *(const unsigned int*)&hc[(size_t)pb.x * OUT_ + fl];
        float wa = __int_as_float(pa.y), wb = __int_as_float(pb.y);
        acc0 += wa * bflo(va); acc1 += wa * bfhi(va);
        acc0 += wb * bflo(vb); acc1 += wb * bfhi(vb);
    }
    if (j < e) {
        int2 p = ecsr[j];
        unsigned int v = *(const unsigned int*)&hc[(size_t)p.x * OUT_ + fl];
        float w = __int_as_float(p.y);
        acc0 += w * bflo(v);
        acc1 += w * bfhi(v);
    }

    acc0 += __shfl_xor(acc0, 32);
    acc1 += __shfl_xor(acc1, 32);

    if (lane < 32) {
        float g = gamma[k];
        size_t o = (size_t)node * OUT_ + fl;
        unsigned int packed = (unsigned int)f2bf(acc0) | ((unsigned int)f2bf(acc1) << 16);
        *(unsigned int*)&hn[o] = packed;
        float2* op = (float2*)&out[o];
        float2 ov = *op;
        ov.x += g * acc0;
        ov.y += g * acc1;
        *op = ov;
    }
}

// ---------------- launcher ----------------
extern "C" void kernel_launch(void* const* d_in, const int* in_sizes, int n_in,
                              void* d_out, int out_size, void* d_ws, size_t ws_size,
                              hipStream_t stream) {
    const float* x = (const float*)d_in[0];
    const int* ei = (const int*)d_in[1];
    const float* W1 = (const float*)d_in[2];
    const float* b1 = (const float*)d_in[3];
    const float* W2 = (const float*)d_in[4];
    const float* b2 = (const float*)d_in[5];
    const float* alpha = (const float*)d_in[6];
    const int* row = ei;
    const int* col = ei + N_EDGES;
    float* out = (float*)d_out;

    const int NBLK = (N_NODES + 255) / 256;  // 391

    char* wsb = (char*)d_ws;
    size_t p = 0;
    auto alloc = [&](size_t bytes) { size_t r = p; p += (bytes + 255) & ~255ull; return r; };
    float* gamma = (float*)(wsb + alloc(16 * 4));
    int* off     = (int*)(wsb + alloc((N_NODES + 1) * 4));
    int* cursor  = (int*)(wsb + alloc(N_NODES * 4));
    int* deg     = (int*)(wsb + alloc(N_NODES * 4));
    float* dis   = (float*)(wsb + alloc(N_NODES * 4));
    int* bsum    = (int*)(wsb + alloc(512 * 4));
    unsigned short* w1T = (unsigned short*)(wsb + alloc((size_t)IN_DIM_ * HID_ * 2));  // [n][k]
    unsigned short* w2T = (unsigned short*)(wsb + alloc((size_t)HID_ * OUT_ * 2));     // [n][k]
    int2* ecsr   = (int2*)(wsb + alloc((size_t)N_EDGES * 8));
    unsigned short* h1  = (unsigned short*)(wsb + alloc((size_t)N_NODES * HID_ * 2));  // 51.2MB
    unsigned short* h_a = (unsigned short*)(wsb + alloc((size_t)N_NODES * OUT_ * 2));  // 12.8MB
    unsigned short* h_b = h1;  // h1 dead after gemm2

    hipMemsetAsync(cursor, 0, N_NODES * sizeof(int), stream);
    hipMemsetAsync(deg, 0, N_NODES * sizeof(int), stream);
    gamma_kernel<<<1, 64, 0, stream>>>(alpha, gamma);
    deg_kernel<<<(N_EDGES + 255) / 256, 256, 0, stream>>>(row, deg, N_EDGES);
    dis_kernel<<<NBLK, 256, 0, stream>>>(deg, dis, N_NODES);
    scan_sum_kernel<<<NBLK, 256, 0, stream>>>(deg, bsum, N_NODES);
    scan_block_kernel<<<1, 512, 0, stream>>>(bsum, off, NBLK, N_NODES);
    scan_final_kernel<<<NBLK, 256, 0, stream>>>(deg, bsum, off, N_NODES);
    csr_scatter_kernel<<<(N_EDGES + 255) / 256, 256, 0, stream>>>(row, col, dis, off, cursor,
                                                                  ecsr, N_EDGES);
    wcast_kernel<<<dim3(1, HID_), 256, 0, stream>>>(W1, w1T, IN_DIM_, HID_);
    wcast_kernel<<<dim3(1, OUT_), 256, 0, stream>>>(W2, w2T, HID_, OUT_);

    gemm1_kernel<<<(N_NODES + 63) / 64, 256, 0, stream>>>(x, w1T, b1, h1, N_NODES);
    gemm2_kernel<<<(N_NODES + 63) / 64, 256, 0, stream>>>(h1, w2T, b2, gamma, h_a, out, N_NODES);

    unsigned short* hc = h_a;
    unsigned short* hn = h_b;
    for (int k = 1; k <= KSTEPS; ++k) {
        pull_kernel<<<(N_NODES + 3) / 4, 256, 0, stream>>>(off, ecsr, hc, hn, out, gamma, k,
                                                           N_NODES);
        unsigned short* t = hc; hc = hn; hn = t;
    }
}